// Round 10
// baseline (4262.451 us; speedup 1.0000x reference)
//
#include <hip/hip_runtime.h>
#include <math.h>

// TransformerCell — flag-fused dataflow + x8 replicas + SINGLE-WAVE POLLING.
// 256 blocks x 512 threads. R9 + two changes:
//  1) Only wave 7 polls chunk buffers (lane l covers 8 consecutive chunks,
//     one vmcnt wait per sweep) -> 8x less poll traffic into the LLC; other
//     waves wait at __syncthreads (no memory traffic).
//  2) Compute waves prefetch weight rows into registers BEFORE the staging
//     barrier (independent of x), removing weight-load latency post-detect.
// Everything else identical to R9 (see its header for the safety argument).

#define NTHR 512
#define NBLK 256

#define B_AC  4096     /* aC  [8][256] chunks */
#define B_SM  36864    /* smC [8][512] */
#define B_C   102400   /* cCh [8][512] */
#define B_D   167936   /* dCh [8][512] */
#define B_E   233472   /* eCh [8][512] */
#define B_ZM  299008   /* zmC [8][512] */
#define B_DCC 364544   /* dCc float[257][1024], pre-scaled 1/32 */

typedef int i4 __attribute__((ext_vector_type(4)));

__device__ __forceinline__ float i2f(int x) { return __int_as_float(x); }
__device__ __forceinline__ int f2i(float x) { return __float_as_int(x); }

__device__ __forceinline__ void astore(float* p, float v) {
  __hip_atomic_store(p, v, __ATOMIC_RELAXED, __HIP_MEMORY_SCOPE_AGENT);
}
__device__ __forceinline__ int aloadI(const int* p) {
  return __hip_atomic_load((int*)p, __ATOMIC_RELAXED, __HIP_MEMORY_SCOPE_AGENT);
}
__device__ __forceinline__ int afaddI(int* p) {
  return __hip_atomic_fetch_add(p, 1, __ATOMIC_RELAXED, __HIP_MEMORY_SCOPE_AGENT);
}

__device__ __forceinline__ void store16(i4* p, i4 v) {
  asm volatile("global_store_dwordx4 %0, %1, off sc0 sc1" :: "v"(p), "v"(v) : "memory");
}

// wave-7 poll: lane covers CPL consecutive chunks; payload (x,y) -> dst pairs
template<int CPL>
__device__ __forceinline__ void wpoll(const i4* base, int tag, int lane, float* dst) {
  i4 v[CPL];
  int got = 0;
  const int full = (1 << CPL) - 1;
  for (;;) {
#pragma unroll
    for (int k = 0; k < CPL; ++k)
      if (!(got & (1 << k)))
        asm volatile("global_load_dwordx4 %0, %1, off sc0 sc1"
                     : "=v"(v[k]) : "v"(base + CPL * lane + k) : "memory");
    asm volatile("s_waitcnt vmcnt(0)" ::: "memory");
#pragma unroll
    for (int k = 0; k < CPL; ++k)
      if (!(got & (1 << k)) && v[k].w == tag) {
        got |= 1 << k;
        dst[2 * (CPL * lane + k)] = i2f(v[k].x);
        dst[2 * (CPL * lane + k) + 1] = i2f(v[k].y);
      }
    if (__all(got == full)) return;
    __builtin_amdgcn_s_sleep(1);
  }
}
// variant for aC: x->dA[i], y->dB[i]  (CPL=4, 256 chunks)
__device__ __forceinline__ void wpoll2(const i4* base, int tag, int lane,
                                       float* dA, float* dB) {
  i4 v[4];
  int got = 0;
  for (;;) {
#pragma unroll
    for (int k = 0; k < 4; ++k)
      if (!(got & (1 << k)))
        asm volatile("global_load_dwordx4 %0, %1, off sc0 sc1"
                     : "=v"(v[k]) : "v"(base + 4 * lane + k) : "memory");
    asm volatile("s_waitcnt vmcnt(0)" ::: "memory");
#pragma unroll
    for (int k = 0; k < 4; ++k)
      if (!(got & (1 << k)) && v[k].w == tag) {
        got |= 1 << k;
        dA[4 * lane + k] = i2f(v[k].x);
        dB[4 * lane + k] = i2f(v[k].y);
      }
    if (__all(got == 15)) return;
    __builtin_amdgcn_s_sleep(1);
  }
}

__device__ __forceinline__ float wred(float v) {
#pragma unroll
  for (int o = 1; o < 64; o <<= 1) v += __shfl_xor(v, o, 64);
  return v;
}
__device__ __forceinline__ void wred2(float& a, float& b) {
#pragma unroll
  for (int o = 1; o < 64; o <<= 1) { a += __shfl_xor(a, o, 64); b += __shfl_xor(b, o, 64); }
}
__device__ __forceinline__ float wmax(float v) {
#pragma unroll
  for (int o = 1; o < 64; o <<= 1) v = fmaxf(v, __shfl_xor(v, o, 64));
  return v;
}
__device__ __forceinline__ float lrelu(float x) { return x > 0.f ? x : 0.01f * x; }

__device__ __forceinline__ void gsync1(int* bar, int bid, int tid, int lane) {
  asm volatile("" ::: "memory");
  __builtin_amdgcn_s_waitcnt(0);
  __syncthreads();
  if (tid == 0) afaddI(bar + (bid & 7) * 16);
  if (tid < 64) {
    for (;;) {
      int v = (lane < 8) ? aloadI(bar + lane * 16) : 0x7fffffff;
      if (__all(v >= 32)) break;
      __builtin_amdgcn_s_sleep(2);
    }
  }
  __syncthreads();
  asm volatile("" ::: "memory");
}

__global__ void __launch_bounds__(NTHR) tcell(
    const float* __restrict__ mu, const float* __restrict__ z0,
    const float* __restrict__ W1, const float* __restrict__ W2, const float* __restrict__ W3,
    const float* __restrict__ p_in_w, const float* __restrict__ p_in_b,
    const float* __restrict__ p_h0_w, const float* __restrict__ p_h0_b,
    const float* __restrict__ p_h1_w, const float* __restrict__ p_h1_b,
    const float* __restrict__ p_out_w, const float* __restrict__ p_out_b,
    const float* __restrict__ m_in_w, const float* __restrict__ m_in_b,
    const float* __restrict__ m_h0_w, const float* __restrict__ m_h0_b,
    const float* __restrict__ m_h1_w, const float* __restrict__ m_h1_b,
    const float* __restrict__ m_out_w, const float* __restrict__ m_out_b,
    float* __restrict__ Z, float* __restrict__ ws) {
  const int tid = threadIdx.x;
  const int bid = blockIdx.x;
  const int lane = tid & 63;
  const int wave = tid >> 6;            // 0..7
  const int r = 4 * bid + (wave & 3);
  const int rep = bid & 7;

  char* wsb = (char*)ws;
  int* bar = (int*)wsb;
  i4* aC  = (i4*)(wsb + B_AC);
  i4* smC = (i4*)(wsb + B_SM);
  i4* cCh = (i4*)(wsb + B_C);
  i4* dCh = (i4*)(wsb + B_D);
  i4* eCh = (i4*)(wsb + B_E);
  i4* zmC = (i4*)(wsb + B_ZM);
  float* dCc = (float*)(wsb + B_DCC);
  i4* aCr  = aC  + rep * 256;
  i4* smCr = smC + rep * 512;
  i4* cChr = cCh + rep * 512;
  i4* dChr = dCh + rep * 512;
  i4* eChr = eCh + rep * 512;
  i4* zmCr = zmC + rep * 512;

  __shared__ float sZ[1024], sX[1024];
  __shared__ float sR[256], sLg[256], sLp[256];
  __shared__ float sU[4][257];
  __shared__ float shW[4], shQ[4], shF[4];

  // ---- P0: waves 0-3 build B=W1@W2, W~=m_in_w@W3 rows (regs); wave 4: p_in
  float4 rB4[4], rW4[4];
  if (wave < 4) {
#pragma unroll
    for (int q = 0; q < 4; ++q) {
      rB4[q] = make_float4(0.f, 0.f, 0.f, 0.f);
      rW4[q] = make_float4(0.f, 0.f, 0.f, 0.f);
    }
    const float* __restrict__ w1r = W1 + (size_t)r * 512;
    const float* __restrict__ mir = m_in_w + (size_t)r * 512;
    for (int k = 0; k < 512; k += 2) {
      float w1a = w1r[k], w1b = w1r[k + 1];
      float mia = mir[k], mib = mir[k + 1];
      const float* w2a = W2 + (size_t)k * 1024 + 4 * lane;
      const float* w3a = W3 + (size_t)k * 1024 + 4 * lane;
#pragma unroll
      for (int q = 0; q < 4; ++q) {
        float4 a0 = *(const float4*)(w2a + 256 * q);
        float4 a1 = *(const float4*)(w2a + 1024 + 256 * q);
        float4 b0 = *(const float4*)(w3a + 256 * q);
        float4 b1 = *(const float4*)(w3a + 1024 + 256 * q);
        rB4[q].x = fmaf(w1a, a0.x, fmaf(w1b, a1.x, rB4[q].x));
        rB4[q].y = fmaf(w1a, a0.y, fmaf(w1b, a1.y, rB4[q].y));
        rB4[q].z = fmaf(w1a, a0.z, fmaf(w1b, a1.z, rB4[q].z));
        rB4[q].w = fmaf(w1a, a0.w, fmaf(w1b, a1.w, rB4[q].w));
        rW4[q].x = fmaf(mia, b0.x, fmaf(mib, b1.x, rW4[q].x));
        rW4[q].y = fmaf(mia, b0.y, fmaf(mib, b1.y, rW4[q].y));
        rW4[q].z = fmaf(mia, b0.z, fmaf(mib, b1.z, rW4[q].z));
        rW4[q].w = fmaf(mia, b0.w, fmaf(mib, b1.w, rW4[q].w));
      }
    }
  } else if (wave == 4) {
    float f[4];
#pragma unroll
    for (int j = 0; j < 4; ++j) {
      int row = 4 * bid + j;
      float acc = p_in_w[(size_t)row * 64 + lane] * mu[lane];
      acc = wred(acc);
      f[j] = lrelu(acc + p_in_b[row]);
    }
    if (lane < 16) {
      int rp = lane >> 1, ch = lane & 1;
      i4 c; c.x = f2i(f[2 * ch]); c.y = f2i(f[2 * ch + 1]); c.z = 0; c.w = 1;
      store16(smC + rp * 512 + 2 * bid + ch, c);
    }
  }

  // dense matvec phase: prefetch weights, wave-7 stage, compute, fire
#define MVP(WPTR, BPTR, ACT, INC, INTAG, OUTC, OUTTAG)                         \
  {                                                                            \
    float4 wreg[4];                                                            \
    if (wave < 4) {                                                            \
      const float* w = (WPTR) + (size_t)r * 1024 + 4 * lane;                   \
      _Pragma("unroll")                                                        \
      for (int q = 0; q < 4; ++q) wreg[q] = *(const float4*)(w + 256 * q);     \
    }                                                                          \
    if (wave == 7) wpoll<8>((INC), (INTAG), lane, sX);                         \
    __syncthreads();                                                           \
    if (wave < 4) {                                                            \
      float acc = 0.f;                                                         \
      _Pragma("unroll")                                                        \
      for (int q = 0; q < 4; ++q) {                                            \
        float4 xf = *(const float4*)(sX + 4 * lane + 256 * q);                 \
        acc = fmaf(wreg[q].x, xf.x, acc); acc = fmaf(wreg[q].y, xf.y, acc);    \
        acc = fmaf(wreg[q].z, xf.z, acc); acc = fmaf(wreg[q].w, xf.w, acc);    \
      }                                                                        \
      acc = wred(acc);                                                         \
      if (lane == 0) {                                                         \
        float vv = acc + (BPTR)[r];                                            \
        shF[wave] = (ACT) ? lrelu(vv) : vv;                                    \
      }                                                                        \
    }                                                                          \
    __syncthreads();                                                           \
    if (tid < 16) {                                                            \
      int rp = tid >> 1, ch = tid & 1;                                         \
      i4 c; c.x = f2i(shF[2 * ch]); c.y = f2i(shF[2 * ch + 1]); c.z = 0;       \
      c.w = (OUTTAG);                                                          \
      store16((OUTC) + rp * 512 + 2 * bid + ch, c);                            \
    }                                                                          \
  }

  // ---- P1..P3
  MVP(p_h0_w, p_h0_b, 1, smCr, 1, cCh, 1)
  MVP(p_h1_w, p_h1_b, 1, cChr, 1, dCh, 1)
  MVP(p_out_w, p_out_b, 0, dChr, 1, zmC, 1)
  if (tid == 16) *(float4*)(Z + 4 * bid) = make_float4(shF[0], shF[1], shF[2], shF[3]);
  if (bid < 2) Z[1024 + bid * 512 + tid] = z0[bid * 512 + tid];

  // ---- P4: append row 0 (d_0 scaled -> dCc, U_0 -> sU)
  if (wave == 7) wpoll<8>(zmCr, 1, lane, sZ);
  __syncthreads();
  if (wave < 4) {
    float aD = 0.f, aU = 0.f;
#pragma unroll
    for (int q = 0; q < 4; ++q) {
      float4 zf = *(const float4*)(sZ + 4 * lane + 256 * q);
      aD = fmaf(rB4[q].x, zf.x, aD); aD = fmaf(rB4[q].y, zf.y, aD);
      aD = fmaf(rB4[q].z, zf.z, aD); aD = fmaf(rB4[q].w, zf.w, aD);
      aU = fmaf(rW4[q].x, zf.x, aU); aU = fmaf(rW4[q].y, zf.y, aU);
      aU = fmaf(rW4[q].z, zf.z, aU); aU = fmaf(rW4[q].w, zf.w, aU);
    }
    wred2(aD, aU);
    if (lane == 0) { astore(dCc + r, aD * 0.03125f); sU[wave][0] = aU; }
  }
  gsync1(bar, bid, tid, lane);    // only barrier: dCc row-0 cross-block writes

  float zprev_e = 0.f, mob = 0.f;
  if (wave < 4) { zprev_e = z0[r]; mob = m_out_b[r]; }

  // ---- main recurrence (pure dataflow)
  for (int t = 2; t <= 256; ++t) {
    // ---------- Phase A ----------
    if (t == 2) {
      *(float2*)(sZ + 2 * tid) = *(const float2*)(z0 + 2 * tid);
    } else {
      if (wave == 7) wpoll<8>(eChr, t - 1, lane, sZ);
    }
    __syncthreads();
    if (wave < 4) {
      float aD = 0.f, aU = 0.f;
#pragma unroll
      for (int q = 0; q < 4; ++q) {
        float4 zf = *(const float4*)(sZ + 4 * lane + 256 * q);
        aD = fmaf(rB4[q].x, zf.x, aD); aD = fmaf(rB4[q].y, zf.y, aD);
        aD = fmaf(rB4[q].z, zf.z, aD); aD = fmaf(rB4[q].w, zf.w, aD);
        aU = fmaf(rW4[q].x, zf.x, aU); aU = fmaf(rW4[q].y, zf.y, aU);
        aU = fmaf(rW4[q].z, zf.z, aU); aU = fmaf(rW4[q].w, zf.w, aU);
      }
      wred2(aD, aU);
      if (lane == 0) {
        float dsc = aD * 0.03125f;
        astore(dCc + (size_t)(t - 1) * 1024 + r, dsc);
        sU[wave][t - 1] = aU;
        shW[wave] = dsc * sZ[r];
      }
    } else {
      float part = 0.f;
      if (bid <= t - 2) {
        const float* dr = dCc + (size_t)bid * 1024 + 256 * (wave - 4) + 4 * lane;
        float4 d4 = *(const float4*)dr;
        const float* zz = sZ + 256 * (wave - 4) + 4 * lane;
        part = d4.x * zz[0] + d4.y * zz[1] + d4.z * zz[2] + d4.w * zz[3];
      }
      part = wred(part);
      if (lane == 0) shQ[wave - 4] = part;
    }
    __builtin_amdgcn_s_waitcnt(0);    // drain dCc stores before evidencing chunk
    __syncthreads();
    if (tid < 8) {
      i4 c; c.x = f2i(shQ[0] + shQ[1] + shQ[2] + shQ[3]);
      c.y = f2i(shW[0] + shW[1] + shW[2] + shW[3]); c.z = 0; c.w = t;
      store16(aC + tid * 256 + bid, c);
    }

    // ---------- Phase SM (single-wave softmax) ----------
    if (wave == 7) wpoll2(aCr, t, lane, sLg, sLp);
    __syncthreads();
    if (wave == 0) {
      float p = sLp[lane] + sLp[lane + 64] + sLp[lane + 128] + sLp[lane + 192];
      p = wred(p);                      // new-row logit (pre-scaled)
      float l[4]; float mx = -1e30f;
#pragma unroll
      for (int j = 0; j < 4; ++j) {
        int i = lane + 64 * j;
        float li = (i <= t - 2) ? sLg[i] : ((i == t - 1) ? p : -1e30f);
        l[j] = li; mx = fmaxf(mx, li);
      }
      mx = wmax(mx);
      float m = fmaxf(mx, 0.f);
      float e[4], es = 0.f;
#pragma unroll
      for (int j = 0; j < 4; ++j) {
        int i = lane + 64 * j;
        e[j] = (i <= t - 1) ? __expf(l[j] - m) : 0.f;
        es += e[j];
      }
      es = wred(es);
      float inv = 1.f / (es + (float)(257 - t) * __expf(-m));
#pragma unroll
      for (int j = 0; j < 4; ++j) sR[lane + 64 * j] = e[j] * inv;
    }
    __syncthreads();
    if (wave < 4) {
      float acc = 0.f;
#pragma unroll
      for (int j = 0; j < 4; ++j) {
        int i = lane + 64 * j;
        if (i <= t - 1) acc = fmaf(sR[i], sU[wave][i], acc);
      }
      acc = wred(acc);
      if (lane == 0) shF[wave] = lrelu(acc + m_in_b[r]);
    }
    __syncthreads();
    if (tid < 16) {
      int rp = tid >> 1, ch = tid & 1;
      i4 c; c.x = f2i(shF[2 * ch]); c.y = f2i(shF[2 * ch + 1]); c.z = 0; c.w = t;
      store16(smC + rp * 512 + 2 * bid + ch, c);
    }

    // ---------- Phase C ----------
    MVP(m_h0_w, m_h0_b, 1, smCr, t, cCh, t)

    // ---------- Phase D ----------
    MVP(m_h1_w, m_h1_b, 1, cChr, t, dCh, t)

    // ---------- Phase E ----------
    {
      float4 wreg[4];
      if (wave < 4) {
        const float* w = m_out_w + (size_t)r * 1024 + 4 * lane;
#pragma unroll
        for (int q = 0; q < 4; ++q) wreg[q] = *(const float4*)(w + 256 * q);
      }
      if (wave == 7) wpoll<8>(dChr, t, lane, sX);
      __syncthreads();
      if (wave < 4) {
        float acc = 0.f;
#pragma unroll
        for (int q = 0; q < 4; ++q) {
          float4 xf = *(const float4*)(sX + 4 * lane + 256 * q);
          acc = fmaf(wreg[q].x, xf.x, acc); acc = fmaf(wreg[q].y, xf.y, acc);
          acc = fmaf(wreg[q].z, xf.z, acc); acc = fmaf(wreg[q].w, xf.w, acc);
        }
        acc = wred(acc);
        float znew = zprev_e + acc + mob;
        zprev_e = znew;
        if (lane == 0) shF[wave] = znew;
      }
      __syncthreads();
      if (tid < 16) {
        int rp = tid >> 1, ch = tid & 1;
        i4 c; c.x = f2i(shF[2 * ch]); c.y = f2i(shF[2 * ch + 1]); c.z = 0; c.w = t;
        store16(eCh + rp * 512 + 2 * bid + ch, c);
      }
      if (tid == 16)
        *(float4*)(Z + (size_t)t * 1024 + 4 * bid) =
            make_float4(shF[0], shF[1], shF[2], shF[3]);
    }
  }
}

extern "C" void kernel_launch(void* const* d_in, const int* in_sizes, int n_in,
                              void* d_out, int out_size, void* d_ws, size_t ws_size,
                              hipStream_t stream) {
  (void)in_sizes; (void)n_in; (void)out_size; (void)ws_size;
  hipMemsetAsync(d_ws, 0, 364544, stream);  // barrier + all replica chunk tags
  tcell<<<dim3(NBLK), dim3(NTHR), 0, stream>>>(
      (const float*)d_in[0],  (const float*)d_in[1],
      (const float*)d_in[2],  (const float*)d_in[3],  (const float*)d_in[4],
      (const float*)d_in[5],  (const float*)d_in[6],
      (const float*)d_in[7],  (const float*)d_in[8],
      (const float*)d_in[9],  (const float*)d_in[10],
      (const float*)d_in[11], (const float*)d_in[12],
      (const float*)d_in[13], (const float*)d_in[14],
      (const float*)d_in[15], (const float*)d_in[16],
      (const float*)d_in[17], (const float*)d_in[18],
      (const float*)d_in[19], (const float*)d_in[20],
      (float*)d_out, (float*)d_ws);
}